// Round 4
// baseline (375.225 us; speedup 1.0000x reference)
//
#include <hip/hip_runtime.h>
#include <stdint.h>
#include <math.h>

// ---------------------------------------------------------------------------
// EstimateNorm: Umeyama best-of-5 template fit + affine warps.
// Outputs (concat, float32):
//   o0 = 0        : xs            (N,5,2)        10*N
//   o1 = 10N      : IM_composed   (N,2,3)         6*N
//   o2 = 16N      : imgs_u8 NHWC  (N,224,224,3)  150528*N   (uint8 values as f32)
//   o3 = 150544N  : t192 NCHW     (N,3,192,192)  110592*N
//   o4 = 261136N  : M             (N,2,3)         6*N
//
// R4: single fused warp kernel. Key facts exploited:
//  - t192 content region is exactly [32,160)x[32,160) (src=1.75*dst-56 maps
//    outside [0,224) elsewhere) -> 55% of t192 is zero, no taps needed.
//  - t224 staged per 32-row strip in LDS (33 rows x 224 packed u8 = 29.6 KB)
//    instead of a 51 MB global workspace. Strip ownership of t192 rows is
//    exact because 1.75*y-56 is exact in fp32.
//  - imgs_u8 written as float3 (dwordx3) -> 1 store inst / px.
// ---------------------------------------------------------------------------

__device__ const float g_src[5][5][2] = {
  {{103.284f,100.23f},{115.234f,99.98f},{71.48f,138.014f},{102.314f,178.1f},{114.05f,179.404f}},
  {{90.062f,100.236f},{131.136f,101.744f},{79.354f,136.222f},{90.354f,172.38f},{128.492f,173.516f}},
  {{79.46f,102.276f},{144.54f,102.276f},{112.0f,136.986f},{84.926f,174.02f},{139.074f,174.02f}},
  {{93.69f,101.744f},{134.764f,100.236f},{145.474f,136.222f},{96.334f,173.516f},{134.472f,172.38f}},
  {{109.592f,99.98f},{121.542f,100.23f},{153.346f,138.014f},{110.776f,179.404f},{122.514f,178.1f}}
};

// Fused: blocks [0, packBlocks) pack img f32x3 -> RGBX u8; the block(s)
// after handle the per-face Umeyama fit.
__global__ void prep_kernel(const float* __restrict__ img,
                            const float* __restrict__ xs,
                            float* __restrict__ out,
                            float* __restrict__ ws_im,
                            uint32_t* __restrict__ pimg,
                            int N, int packBlocks) {
  if ((int)blockIdx.x < packBlocks) {
    uint32_t p = blockIdx.x * blockDim.x + threadIdx.x;  // pixel in [0, 1024^2)
    if (p < 1024u * 1024u) {
      float r = img[(size_t)p * 3 + 0];
      float g = img[(size_t)p * 3 + 1];
      float b = img[(size_t)p * 3 + 2];
      uint32_t ri = (uint32_t)(r + 0.5f);
      uint32_t gi = (uint32_t)(g + 0.5f);
      uint32_t bi = (uint32_t)(b + 0.5f);
      pimg[p] = ri | (gi << 8) | (bi << 16);
    }
    return;
  }

  int n = ((int)blockIdx.x - packBlocks) * blockDim.x + threadIdx.x;
  if (n >= N) return;

  #pragma unroll
  for (int i = 0; i < 10; i++) out[(size_t)n * 10 + i] = xs[(size_t)n * 10 + i];

  float px[5], py[5];
  #pragma unroll
  for (int p = 0; p < 5; p++) {
    px[p] = xs[n * 10 + 2 * p];
    py[p] = xs[n * 10 + 2 * p + 1];
  }
  float smx = 0.f, smy = 0.f;
  #pragma unroll
  for (int p = 0; p < 5; p++) { smx += px[p]; smy += py[p]; }
  smx *= 0.2f; smy *= 0.2f;
  float sdx[5], sdy[5], var_sum = 0.f;
  #pragma unroll
  for (int p = 0; p < 5; p++) {
    sdx[p] = px[p] - smx; sdy[p] = py[p] - smy;
    var_sum += sdx[p] * sdx[p] + sdy[p] * sdy[p];
  }
  var_sum *= 0.2f;

  float bestE = 1e30f;
  float bM[6] = {0, 0, 0, 0, 0, 0};

  for (int k = 0; k < 5; k++) {
    float dmx = 0.f, dmy = 0.f;
    #pragma unroll
    for (int p = 0; p < 5; p++) { dmx += g_src[k][p][0]; dmy += g_src[k][p][1]; }
    dmx *= 0.2f; dmy *= 0.2f;

    float A00 = 0, A01 = 0, A10 = 0, A11 = 0;
    #pragma unroll
    for (int p = 0; p < 5; p++) {
      float ddx = g_src[k][p][0] - dmx;
      float ddy = g_src[k][p][1] - dmy;
      A00 += ddx * sdx[p]; A01 += ddx * sdy[p];
      A10 += ddy * sdx[p]; A11 += ddy * sdy[p];
    }
    A00 *= 0.2f; A01 *= 0.2f; A10 *= 0.2f; A11 *= 0.2f;

    float detA = A00 * A11 - A01 * A10;
    float d1 = (detA > 0.f) ? 1.f : ((detA < 0.f) ? -1.f : 0.f);

    float E = (A00 + A11) * 0.5f, F = (A00 - A11) * 0.5f;
    float G = (A10 + A01) * 0.5f, H = (A10 - A01) * 0.5f;
    float Q = hypotf(E, H), Rr = hypotf(F, G);
    float sxv = Q + Rr, syv = Q - Rr;
    float a1 = atan2f(G, F), a2 = atan2f(H, E);
    float beta = (a2 - a1) * 0.5f, gamma = (a2 + a1) * 0.5f;
    float cg = cosf(gamma), sg = sinf(gamma);
    float cb = cosf(beta),  sb = sinf(beta);
    float sgn = (syv < 0.f) ? -1.f : 1.f;
    float Vt00 = cb, Vt01 = -sb, Vt10 = sb * sgn, Vt11 = cb * sgn;
    float R00 = cg * Vt00 - sg * d1 * Vt10;
    float R01 = cg * Vt01 - sg * d1 * Vt11;
    float R10 = sg * Vt00 + cg * d1 * Vt10;
    float R11 = sg * Vt01 + cg * d1 * Vt11;
    float scale = (sxv + fabsf(syv) * d1) / var_sum;
    float m00 = scale * R00, m01 = scale * R01;
    float m10 = scale * R10, m11 = scale * R11;
    float t0 = dmx - (m00 * smx + m01 * smy);
    float t1 = dmy - (m10 * smx + m11 * smy);

    float e = 0.f;
    #pragma unroll
    for (int p = 0; p < 5; p++) {
      float rx = m00 * px[p] + m01 * py[p] + t0 - g_src[k][p][0];
      float ry = m10 * px[p] + m11 * py[p] + t1 - g_src[k][p][1];
      e += sqrtf(rx * rx + ry * ry);
    }
    if (e < bestE) {
      bestE = e;
      bM[0] = m00; bM[1] = m01; bM[2] = t0;
      bM[3] = m10; bM[4] = m11; bM[5] = t1;
    }
  }

  size_t o1 = (size_t)10 * N;
  size_t o4 = (size_t)261136 * N;

  #pragma unroll
  for (int i = 0; i < 6; i++) out[o4 + (size_t)n * 6 + i] = bM[i];

  float det = bM[0] * bM[4] - bM[1] * bM[3];
  float ia = bM[4] / det, ib = -bM[1] / det;
  float ic = -bM[3] / det, idd = bM[0] / det;
  float itx = -(ia * bM[2] + ib * bM[5]);
  float ity = -(ic * bM[2] + idd * bM[5]);

  ws_im[n * 6 + 0] = ia;  ws_im[n * 6 + 1] = ib;  ws_im[n * 6 + 2] = itx;
  ws_im[n * 6 + 3] = ic;  ws_im[n * 6 + 4] = idd; ws_im[n * 6 + 5] = ity;

  out[o1 + (size_t)n * 6 + 0] = 1.75f * ia;
  out[o1 + (size_t)n * 6 + 1] = 1.75f * ib;
  out[o1 + (size_t)n * 6 + 2] = -56.f * (ia + ib) + itx;
  out[o1 + (size_t)n * 6 + 3] = 1.75f * ic;
  out[o1 + (size_t)n * 6 + 4] = 1.75f * idd;
  out[o1 + (size_t)n * 6 + 5] = -56.f * (ic + idd) + ity;
}

__device__ __forceinline__ void unpack3(uint32_t v, float& r, float& g, float& b) {
  r = (float)(v & 0xffu);
  g = (float)((v >> 8) & 0xffu);
  b = (float)((v >> 16) & 0xffu);
}

struct F3 { float x, y, z; };

// One block per (face, strip). 7 strips of 32 t224-rows per face.
// Phase 1: t224 rows [32s, 32s+33) -> LDS (packed u8) + imgs_u8 float3 out.
// Phase 2: t192 rows owned by this strip (content + zero borders).
__global__ __launch_bounds__(256) void fused_warp_kernel(
    const uint32_t* __restrict__ pimg,
    const float* __restrict__ IMs,
    float* __restrict__ out_u8,
    float* __restrict__ out192,
    int N) {
  __shared__ uint32_t lds[33 * 224];

  int bid = blockIdx.x;
  int s = bid % 7;
  int n = bid / 7;
  int tid = threadIdx.x;
  int r0 = 32 * s;
  int rows = (s == 6) ? 32 : 33;

  const float* IM = IMs + (size_t)n * 6;
  float im0 = IM[0], im1 = IM[1], im2 = IM[2];
  float im3 = IM[3], im4 = IM[4], im5 = IM[5];

  // ---- Phase 1: stage t224 strip into LDS, emit imgs_u8 ----
  int tot1 = rows * 224;
  for (int i = tid; i < tot1; i += 256) {
    int lr = i / 224;
    int x = i - lr * 224;
    int r = r0 + lr;
    float gx = (float)x, gy = (float)r;
    float sx = im0 * gx + im1 * gy + im2;
    float sy = im3 * gx + im4 * gy + im5;

    float x0f = floorf(sx), y0f = floorf(sy);
    float fx = sx - x0f, fy = sy - y0f;
    int x0 = (int)x0f, y0 = (int)y0f;
    int x1 = x0 + 1, y1 = y0 + 1;
    bool vx0 = (x0 >= 0) & (x0 < 1024), vx1 = (x1 >= 0) & (x1 < 1024);
    bool vy0 = (y0 >= 0) & (y0 < 1024), vy1 = (y1 >= 0) & (y1 < 1024);
    int x0c = min(max(x0, 0), 1023), x1c = min(max(x1, 0), 1023);
    int y0c = min(max(y0, 0), 1023), y1c = min(max(y1, 0), 1023);
    float w00 = (1.0f - fx) * (1.0f - fy) * (float)(vx0 & vy0);
    float w10 = fx * (1.0f - fy)          * (float)(vx1 & vy0);
    float w01 = (1.0f - fx) * fy          * (float)(vx0 & vy1);
    float w11 = fx * fy                   * (float)(vx1 & vy1);

    uint32_t p00 = pimg[(uint32_t)y0c * 1024u + (uint32_t)x0c];
    uint32_t p10 = pimg[(uint32_t)y0c * 1024u + (uint32_t)x1c];
    uint32_t p01 = pimg[(uint32_t)y1c * 1024u + (uint32_t)x0c];
    uint32_t p11 = pimg[(uint32_t)y1c * 1024u + (uint32_t)x1c];

    float r00, g00, b00, r10, g10, b10, r01, g01, b01, r11, g11, b11;
    unpack3(p00, r00, g00, b00);
    unpack3(p10, r10, g10, b10);
    unpack3(p01, r01, g01, b01);
    unpack3(p11, r11, g11, b11);

    float vr = r00 * w00 + r10 * w10 + r01 * w01 + r11 * w11;
    float vg = g00 * w00 + g10 * w10 + g01 * w01 + g11 * w11;
    float vb = b00 * w00 + b10 * w10 + b01 * w01 + b11 * w11;

    // staged (round-to-nearest) for the 192-warp
    uint32_t ri = (uint32_t)(vr + 0.5f);
    uint32_t gi = (uint32_t)(vg + 0.5f);
    uint32_t bi = (uint32_t)(vb + 0.5f);
    lds[i] = ri | (gi << 8) | (bi << 16);

    // imgs_u8 (truncated) — only the 32 owned rows (overlap row belongs to s+1)
    if (lr < 32) {
      size_t ob = (((size_t)n * 224 + (size_t)r) * 224 + (size_t)x) * 3;
      F3 v; v.x = (float)(uint32_t)vr; v.y = (float)(uint32_t)vg; v.z = (float)(uint32_t)vb;
      *(F3*)(out_u8 + ob) = v;
    }
  }
  __syncthreads();

  // ---- Phase 2: t192 rows owned by this strip ----
  // content rows: floor(1.75y-56) in [32s, 32s+31]  ->  y in [ylo, yhi)
  int ylo = (128 * s + 230) / 7;   // ceil((32s+56)/1.75)
  int yhi = (128 * s + 358) / 7;   // ceil((32s+88)/1.75)
  int crows = yhi - ylo;

  float* o192n = out192 + (size_t)n * 110592u;

  // 2a: content pixels, x in [32,160): all 4 taps valid & in-strip
  int tot2 = crows * 128;
  for (int i = tid; i < tot2; i += 256) {
    int ly = i >> 7;
    int x = (i & 127) + 32;
    int y = ylo + ly;
    float sy = 1.75f * (float)y - 56.0f;   // exact in fp32
    float sx = 1.75f * (float)x - 56.0f;
    int y0 = (int)sy;                       // sy >= 0 here: trunc == floor
    int x0 = (int)sx;
    float fy = sy - (float)y0;
    float fx = sx - (float)x0;
    int lyr = y0 - r0;
    const uint32_t* row0 = &lds[lyr * 224 + x0];
    uint32_t p00 = row0[0], p10 = row0[1];
    uint32_t p01 = row0[224], p11 = row0[225];

    float w00 = (1.0f - fx) * (1.0f - fy);
    float w10 = fx * (1.0f - fy);
    float w01 = (1.0f - fx) * fy;
    float w11 = fx * fy;

    float r00, g00, b00, r10, g10, b10, r01, g01, b01, r11, g11, b11;
    unpack3(p00, r00, g00, b00);
    unpack3(p10, r10, g10, b10);
    unpack3(p01, r01, g01, b01);
    unpack3(p11, r11, g11, b11);

    float vr = r00 * w00 + r10 * w10 + r01 * w01 + r11 * w11;
    float vg = g00 * w00 + g10 * w10 + g01 * w01 + g11 * w11;
    float vb = b00 * w00 + b10 * w10 + b01 * w01 + b11 * w11;

    size_t base = (size_t)y * 192u + (size_t)x;
    o192n[base]          = vr;
    o192n[base + 36864u] = vg;
    o192n[base + 73728u] = vb;
  }

  // 2b: zero borders of content rows: x in [0,32) U [160,192)
  int tot3 = crows * 64;
  for (int i = tid; i < tot3; i += 256) {
    int ly = i >> 6;
    int xx = i & 63;
    int x = (xx < 32) ? xx : (xx + 128);
    int y = ylo + ly;
    size_t base = (size_t)y * 192u + (size_t)x;
    o192n[base]          = 0.f;
    o192n[base + 36864u] = 0.f;
    o192n[base + 73728u] = 0.f;
  }

  // 2c: fully-zero rows (strip 0 -> rows 0..31, strip 6 -> rows 160..191)
  if (s == 0 || s == 6) {
    int yb = (s == 0) ? 0 : 160;
    int tot4 = 32 * 192;
    for (int i = tid; i < tot4; i += 256) {
      int y = yb + i / 192;
      int x = i - (i / 192) * 192;
      size_t base = (size_t)y * 192u + (size_t)x;
      o192n[base]          = 0.f;
      o192n[base + 36864u] = 0.f;
      o192n[base + 73728u] = 0.f;
    }
  }
}

extern "C" void kernel_launch(void* const* d_in, const int* in_sizes, int n_in,
                              void* d_out, int out_size, void* d_ws, size_t ws_size,
                              hipStream_t stream) {
  const float* xs  = (const float*)d_in[0];
  const float* img = (const float*)d_in[1];
  float* out = (float*)d_out;

  int N = in_sizes[0] / 10;  // 256

  // ws layout (bytes): [0, 24N) IM floats; [8192, +4MB) packed img.
  char* ws = (char*)d_ws;
  float*    ws_im = (float*)ws;
  uint32_t* pimg  = (uint32_t*)(ws + 8192);

  float* out_u8 = out + (size_t)16 * N;
  float* out192 = out + (size_t)150544 * N;

  // 1) fused pack + estimate
  {
    int packBlocks = (1024 * 1024) / 256;          // 4096
    int estBlocks = (N + 255) / 256;
    hipLaunchKernelGGL(prep_kernel, dim3(packBlocks + estBlocks), dim3(256), 0,
                       stream, img, xs, out, ws_im, pimg, N, packBlocks);
  }
  // 2) fused warp: imgs_u8 + t192 in one pass, t224 staged in LDS
  {
    hipLaunchKernelGGL(fused_warp_kernel, dim3((uint32_t)N * 7u), dim3(256), 0,
                       stream, pimg, ws_im, out_u8, out192, N);
  }
}

// Round 5
// 356.075 us; speedup vs baseline: 1.0538x; 1.0538x over previous
//
#include <hip/hip_runtime.h>
#include <stdint.h>
#include <math.h>

// ---------------------------------------------------------------------------
// EstimateNorm: Umeyama best-of-5 template fit + affine warps.
// Outputs (concat, float32):
//   o0 = 0        : xs            (N,5,2)        10*N
//   o1 = 10N      : IM_composed   (N,2,3)         6*N
//   o2 = 16N      : imgs_u8 NHWC  (N,224,224,3)  150528*N   (uint8 values as f32)
//   o3 = 150544N  : t192 NCHW     (N,3,192,192)  110592*N
//   o4 = 261136N  : M             (N,2,3)         6*N
//
// R5: R4 fused structure + NON-TEMPORAL stores on all output streams.
// Theory: the 4 MB packed image == one XCD's L2; the 267 MB store stream
// was evicting it, turning gathers into L3/fabric traffic (~150 us).
// NT stores keep L2 for the gather working set.
// ---------------------------------------------------------------------------

__device__ const float g_src[5][5][2] = {
  {{103.284f,100.23f},{115.234f,99.98f},{71.48f,138.014f},{102.314f,178.1f},{114.05f,179.404f}},
  {{90.062f,100.236f},{131.136f,101.744f},{79.354f,136.222f},{90.354f,172.38f},{128.492f,173.516f}},
  {{79.46f,102.276f},{144.54f,102.276f},{112.0f,136.986f},{84.926f,174.02f},{139.074f,174.02f}},
  {{93.69f,101.744f},{134.764f,100.236f},{145.474f,136.222f},{96.334f,173.516f},{134.472f,172.38f}},
  {{109.592f,99.98f},{121.542f,100.23f},{153.346f,138.014f},{110.776f,179.404f},{122.514f,178.1f}}
};

// Fused: blocks [0, packBlocks) pack img f32x3 -> RGBX u8; the block(s)
// after handle the per-face Umeyama fit.
__global__ void prep_kernel(const float* __restrict__ img,
                            const float* __restrict__ xs,
                            float* __restrict__ out,
                            float* __restrict__ ws_im,
                            uint32_t* __restrict__ pimg,
                            int N, int packBlocks) {
  if ((int)blockIdx.x < packBlocks) {
    uint32_t p = blockIdx.x * blockDim.x + threadIdx.x;  // pixel in [0, 1024^2)
    if (p < 1024u * 1024u) {
      float r = __builtin_nontemporal_load(img + (size_t)p * 3 + 0);
      float g = __builtin_nontemporal_load(img + (size_t)p * 3 + 1);
      float b = __builtin_nontemporal_load(img + (size_t)p * 3 + 2);
      uint32_t ri = (uint32_t)(r + 0.5f);
      uint32_t gi = (uint32_t)(g + 0.5f);
      uint32_t bi = (uint32_t)(b + 0.5f);
      __builtin_nontemporal_store(ri | (gi << 8) | (bi << 16), pimg + p);
    }
    return;
  }

  int n = ((int)blockIdx.x - packBlocks) * blockDim.x + threadIdx.x;
  if (n >= N) return;

  #pragma unroll
  for (int i = 0; i < 10; i++) out[(size_t)n * 10 + i] = xs[(size_t)n * 10 + i];

  float px[5], py[5];
  #pragma unroll
  for (int p = 0; p < 5; p++) {
    px[p] = xs[n * 10 + 2 * p];
    py[p] = xs[n * 10 + 2 * p + 1];
  }
  float smx = 0.f, smy = 0.f;
  #pragma unroll
  for (int p = 0; p < 5; p++) { smx += px[p]; smy += py[p]; }
  smx *= 0.2f; smy *= 0.2f;
  float sdx[5], sdy[5], var_sum = 0.f;
  #pragma unroll
  for (int p = 0; p < 5; p++) {
    sdx[p] = px[p] - smx; sdy[p] = py[p] - smy;
    var_sum += sdx[p] * sdx[p] + sdy[p] * sdy[p];
  }
  var_sum *= 0.2f;

  float bestE = 1e30f;
  float bM[6] = {0, 0, 0, 0, 0, 0};

  for (int k = 0; k < 5; k++) {
    float dmx = 0.f, dmy = 0.f;
    #pragma unroll
    for (int p = 0; p < 5; p++) { dmx += g_src[k][p][0]; dmy += g_src[k][p][1]; }
    dmx *= 0.2f; dmy *= 0.2f;

    float A00 = 0, A01 = 0, A10 = 0, A11 = 0;
    #pragma unroll
    for (int p = 0; p < 5; p++) {
      float ddx = g_src[k][p][0] - dmx;
      float ddy = g_src[k][p][1] - dmy;
      A00 += ddx * sdx[p]; A01 += ddx * sdy[p];
      A10 += ddy * sdx[p]; A11 += ddy * sdy[p];
    }
    A00 *= 0.2f; A01 *= 0.2f; A10 *= 0.2f; A11 *= 0.2f;

    float detA = A00 * A11 - A01 * A10;
    float d1 = (detA > 0.f) ? 1.f : ((detA < 0.f) ? -1.f : 0.f);

    float E = (A00 + A11) * 0.5f, F = (A00 - A11) * 0.5f;
    float G = (A10 + A01) * 0.5f, H = (A10 - A01) * 0.5f;
    float Q = hypotf(E, H), Rr = hypotf(F, G);
    float sxv = Q + Rr, syv = Q - Rr;
    float a1 = atan2f(G, F), a2 = atan2f(H, E);
    float beta = (a2 - a1) * 0.5f, gamma = (a2 + a1) * 0.5f;
    float cg = cosf(gamma), sg = sinf(gamma);
    float cb = cosf(beta),  sb = sinf(beta);
    float sgn = (syv < 0.f) ? -1.f : 1.f;
    float Vt00 = cb, Vt01 = -sb, Vt10 = sb * sgn, Vt11 = cb * sgn;
    float R00 = cg * Vt00 - sg * d1 * Vt10;
    float R01 = cg * Vt01 - sg * d1 * Vt11;
    float R10 = sg * Vt00 + cg * d1 * Vt10;
    float R11 = sg * Vt01 + cg * d1 * Vt11;
    float scale = (sxv + fabsf(syv) * d1) / var_sum;
    float m00 = scale * R00, m01 = scale * R01;
    float m10 = scale * R10, m11 = scale * R11;
    float t0 = dmx - (m00 * smx + m01 * smy);
    float t1 = dmy - (m10 * smx + m11 * smy);

    float e = 0.f;
    #pragma unroll
    for (int p = 0; p < 5; p++) {
      float rx = m00 * px[p] + m01 * py[p] + t0 - g_src[k][p][0];
      float ry = m10 * px[p] + m11 * py[p] + t1 - g_src[k][p][1];
      e += sqrtf(rx * rx + ry * ry);
    }
    if (e < bestE) {
      bestE = e;
      bM[0] = m00; bM[1] = m01; bM[2] = t0;
      bM[3] = m10; bM[4] = m11; bM[5] = t1;
    }
  }

  size_t o1 = (size_t)10 * N;
  size_t o4 = (size_t)261136 * N;

  #pragma unroll
  for (int i = 0; i < 6; i++) out[o4 + (size_t)n * 6 + i] = bM[i];

  float det = bM[0] * bM[4] - bM[1] * bM[3];
  float ia = bM[4] / det, ib = -bM[1] / det;
  float ic = -bM[3] / det, idd = bM[0] / det;
  float itx = -(ia * bM[2] + ib * bM[5]);
  float ity = -(ic * bM[2] + idd * bM[5]);

  ws_im[n * 6 + 0] = ia;  ws_im[n * 6 + 1] = ib;  ws_im[n * 6 + 2] = itx;
  ws_im[n * 6 + 3] = ic;  ws_im[n * 6 + 4] = idd; ws_im[n * 6 + 5] = ity;

  out[o1 + (size_t)n * 6 + 0] = 1.75f * ia;
  out[o1 + (size_t)n * 6 + 1] = 1.75f * ib;
  out[o1 + (size_t)n * 6 + 2] = -56.f * (ia + ib) + itx;
  out[o1 + (size_t)n * 6 + 3] = 1.75f * ic;
  out[o1 + (size_t)n * 6 + 4] = 1.75f * idd;
  out[o1 + (size_t)n * 6 + 5] = -56.f * (ic + idd) + ity;
}

__device__ __forceinline__ void unpack3(uint32_t v, float& r, float& g, float& b) {
  r = (float)(v & 0xffu);
  g = (float)((v >> 8) & 0xffu);
  b = (float)((v >> 16) & 0xffu);
}

// One block per (face, strip). 7 strips of 32 t224-rows per face.
// Phase 1: t224 rows [32s, 32s+33) -> LDS (packed u8) + imgs_u8 out (NT).
// Phase 2: t192 rows owned by this strip (content + zero borders, NT).
__global__ __launch_bounds__(256) void fused_warp_kernel(
    const uint32_t* __restrict__ pimg,
    const float* __restrict__ IMs,
    float* __restrict__ out_u8,
    float* __restrict__ out192,
    int N) {
  __shared__ uint32_t lds[33 * 224];

  int bid = blockIdx.x;
  int s = bid % 7;
  int n = bid / 7;
  int tid = threadIdx.x;
  int r0 = 32 * s;
  int rows = (s == 6) ? 32 : 33;

  const float* IM = IMs + (size_t)n * 6;
  float im0 = IM[0], im1 = IM[1], im2 = IM[2];
  float im3 = IM[3], im4 = IM[4], im5 = IM[5];

  // ---- Phase 1: stage t224 strip into LDS, emit imgs_u8 ----
  int tot1 = rows * 224;
  for (int i = tid; i < tot1; i += 256) {
    int lr = i / 224;
    int x = i - lr * 224;
    int r = r0 + lr;
    float gx = (float)x, gy = (float)r;
    float sx = im0 * gx + im1 * gy + im2;
    float sy = im3 * gx + im4 * gy + im5;

    float x0f = floorf(sx), y0f = floorf(sy);
    float fx = sx - x0f, fy = sy - y0f;
    int x0 = (int)x0f, y0 = (int)y0f;
    int x1 = x0 + 1, y1 = y0 + 1;
    bool vx0 = (x0 >= 0) & (x0 < 1024), vx1 = (x1 >= 0) & (x1 < 1024);
    bool vy0 = (y0 >= 0) & (y0 < 1024), vy1 = (y1 >= 0) & (y1 < 1024);
    int x0c = min(max(x0, 0), 1023), x1c = min(max(x1, 0), 1023);
    int y0c = min(max(y0, 0), 1023), y1c = min(max(y1, 0), 1023);
    float w00 = (1.0f - fx) * (1.0f - fy) * (float)(vx0 & vy0);
    float w10 = fx * (1.0f - fy)          * (float)(vx1 & vy0);
    float w01 = (1.0f - fx) * fy          * (float)(vx0 & vy1);
    float w11 = fx * fy                   * (float)(vx1 & vy1);

    uint32_t p00 = pimg[(uint32_t)y0c * 1024u + (uint32_t)x0c];
    uint32_t p10 = pimg[(uint32_t)y0c * 1024u + (uint32_t)x1c];
    uint32_t p01 = pimg[(uint32_t)y1c * 1024u + (uint32_t)x0c];
    uint32_t p11 = pimg[(uint32_t)y1c * 1024u + (uint32_t)x1c];

    float r00, g00, b00, r10, g10, b10, r01, g01, b01, r11, g11, b11;
    unpack3(p00, r00, g00, b00);
    unpack3(p10, r10, g10, b10);
    unpack3(p01, r01, g01, b01);
    unpack3(p11, r11, g11, b11);

    float vr = r00 * w00 + r10 * w10 + r01 * w01 + r11 * w11;
    float vg = g00 * w00 + g10 * w10 + g01 * w01 + g11 * w11;
    float vb = b00 * w00 + b10 * w10 + b01 * w01 + b11 * w11;

    // staged (round-to-nearest) for the 192-warp
    uint32_t ri = (uint32_t)(vr + 0.5f);
    uint32_t gi = (uint32_t)(vg + 0.5f);
    uint32_t bi = (uint32_t)(vb + 0.5f);
    lds[i] = ri | (gi << 8) | (bi << 16);

    // imgs_u8 (truncated) — only the 32 owned rows; NT stores (streaming)
    if (lr < 32) {
      size_t ob = (((size_t)n * 224 + (size_t)r) * 224 + (size_t)x) * 3;
      __builtin_nontemporal_store((float)(uint32_t)vr, out_u8 + ob + 0);
      __builtin_nontemporal_store((float)(uint32_t)vg, out_u8 + ob + 1);
      __builtin_nontemporal_store((float)(uint32_t)vb, out_u8 + ob + 2);
    }
  }
  __syncthreads();

  // ---- Phase 2: t192 rows owned by this strip ----
  // content rows: floor(1.75y-56) in [32s, 32s+31]  ->  y in [ylo, yhi)
  int ylo = (128 * s + 230) / 7;   // ceil((32s+56)/1.75)
  int yhi = (128 * s + 358) / 7;   // ceil((32s+88)/1.75)
  int crows = yhi - ylo;

  float* o192n = out192 + (size_t)n * 110592u;

  // 2a: content pixels, x in [32,160): all 4 taps valid & in-strip
  int tot2 = crows * 128;
  for (int i = tid; i < tot2; i += 256) {
    int ly = i >> 7;
    int x = (i & 127) + 32;
    int y = ylo + ly;
    float sy = 1.75f * (float)y - 56.0f;   // exact in fp32
    float sx = 1.75f * (float)x - 56.0f;
    int y0 = (int)sy;                       // sy >= 0 here: trunc == floor
    int x0 = (int)sx;
    float fy = sy - (float)y0;
    float fx = sx - (float)x0;
    int lyr = y0 - r0;
    const uint32_t* row0 = &lds[lyr * 224 + x0];
    uint32_t p00 = row0[0], p10 = row0[1];
    uint32_t p01 = row0[224], p11 = row0[225];

    float w00 = (1.0f - fx) * (1.0f - fy);
    float w10 = fx * (1.0f - fy);
    float w01 = (1.0f - fx) * fy;
    float w11 = fx * fy;

    float r00, g00, b00, r10, g10, b10, r01, g01, b01, r11, g11, b11;
    unpack3(p00, r00, g00, b00);
    unpack3(p10, r10, g10, b10);
    unpack3(p01, r01, g01, b01);
    unpack3(p11, r11, g11, b11);

    float vr = r00 * w00 + r10 * w10 + r01 * w01 + r11 * w11;
    float vg = g00 * w00 + g10 * w10 + g01 * w01 + g11 * w11;
    float vb = b00 * w00 + b10 * w10 + b01 * w01 + b11 * w11;

    size_t base = (size_t)y * 192u + (size_t)x;
    __builtin_nontemporal_store(vr, o192n + base);
    __builtin_nontemporal_store(vg, o192n + base + 36864u);
    __builtin_nontemporal_store(vb, o192n + base + 73728u);
  }

  // 2b: zero borders of content rows: x in [0,32) U [160,192)
  int tot3 = crows * 64;
  for (int i = tid; i < tot3; i += 256) {
    int ly = i >> 6;
    int xx = i & 63;
    int x = (xx < 32) ? xx : (xx + 128);
    int y = ylo + ly;
    size_t base = (size_t)y * 192u + (size_t)x;
    __builtin_nontemporal_store(0.f, o192n + base);
    __builtin_nontemporal_store(0.f, o192n + base + 36864u);
    __builtin_nontemporal_store(0.f, o192n + base + 73728u);
  }

  // 2c: fully-zero rows (strip 0 -> rows 0..31, strip 6 -> rows 160..191)
  if (s == 0 || s == 6) {
    int yb = (s == 0) ? 0 : 160;
    int tot4 = 32 * 192;
    for (int i = tid; i < tot4; i += 256) {
      int y = yb + i / 192;
      int x = i - (i / 192) * 192;
      size_t base = (size_t)y * 192u + (size_t)x;
      __builtin_nontemporal_store(0.f, o192n + base);
      __builtin_nontemporal_store(0.f, o192n + base + 36864u);
      __builtin_nontemporal_store(0.f, o192n + base + 73728u);
    }
  }
}

extern "C" void kernel_launch(void* const* d_in, const int* in_sizes, int n_in,
                              void* d_out, int out_size, void* d_ws, size_t ws_size,
                              hipStream_t stream) {
  const float* xs  = (const float*)d_in[0];
  const float* img = (const float*)d_in[1];
  float* out = (float*)d_out;

  int N = in_sizes[0] / 10;  // 256

  // ws layout (bytes): [0, 24N) IM floats; [8192, +4MB) packed img.
  char* ws = (char*)d_ws;
  float*    ws_im = (float*)ws;
  uint32_t* pimg  = (uint32_t*)(ws + 8192);

  float* out_u8 = out + (size_t)16 * N;
  float* out192 = out + (size_t)150544 * N;

  // 1) fused pack + estimate
  {
    int packBlocks = (1024 * 1024) / 256;          // 4096
    int estBlocks = (N + 255) / 256;
    hipLaunchKernelGGL(prep_kernel, dim3(packBlocks + estBlocks), dim3(256), 0,
                       stream, img, xs, out, ws_im, pimg, N, packBlocks);
  }
  // 2) fused warp: imgs_u8 + t192 in one pass, t224 staged in LDS
  {
    hipLaunchKernelGGL(fused_warp_kernel, dim3((uint32_t)N * 7u), dim3(256), 0,
                       stream, pimg, ws_im, out_u8, out192, N);
  }
}